// Round 2
// baseline (40.205 us; speedup 1.0000x reference)
//
#include <hip/hip_runtime.h>

// X = prod_{i=0}^{n-1} (I + A_i/n), left-to-right, A: [N,2,2] f32 row-major.
// Associative -> chunked serial products + ordered tree combines, fp64 accum.
// R1: latency-bound -> 4x grid (32 waves/CU), paired loads for 2 outstanding
// loads/lane; phase2 widened to 256 threads for 8192 partials.

struct M2 { double a, b, c, d; };  // [[a,b],[c,d]]

__device__ __forceinline__ M2 m2mul(const M2& X, const M2& Y) {
    M2 r;
    r.a = fma(X.a, Y.a, X.b * Y.c);
    r.b = fma(X.a, Y.b, X.b * Y.d);
    r.c = fma(X.c, Y.a, X.d * Y.c);
    r.d = fma(X.c, Y.b, X.d * Y.d);
    return r;
}

__device__ __forceinline__ M2 from_f4(float4 v, double inv_n) {
    M2 M;
    M.a = fma((double)v.x, inv_n, 1.0);
    M.b = (double)v.y * inv_n;
    M.c = (double)v.z * inv_n;
    M.d = fma((double)v.w, inv_n, 1.0);
    return M;
}

// Ordered wave tree combine: lower lane = earlier chunk = left operand.
// Lane 0 ends with the product over all 64 lanes.
__device__ __forceinline__ M2 wave_combine(M2 P) {
    #pragma unroll
    for (int off = 1; off < 64; off <<= 1) {
        M2 Q;
        Q.a = __shfl_down(P.a, off);
        Q.b = __shfl_down(P.b, off);
        Q.c = __shfl_down(P.c, off);
        Q.d = __shfl_down(P.d, off);
        P = m2mul(P, Q);
    }
    return P;
}

#define P1_BLOCKS 2048
#define P1_TPB 256
#define T_TOTAL (P1_BLOCKS * P1_TPB)   // 524288 threads
#define N_WAVES (T_TOTAL / 64)         // 8192 wave partials

__global__ void __launch_bounds__(P1_TPB) prodchain_phase1(
    const float4* __restrict__ A, int n, int chunk, double* __restrict__ part)
{
    const int t = blockIdx.x * P1_TPB + threadIdx.x;
    long start = (long)t * chunk;
    long end = start + chunk;
    if (start > n) start = n;
    if (end > n) end = n;
    const double inv_n = 1.0 / (double)n;

    M2 P = {1.0, 0.0, 0.0, 1.0};
    long i = start;
    for (; i + 2 <= end; i += 2) {
        float4 v0 = A[i];
        float4 v1 = A[i + 1];
        P = m2mul(P, from_f4(v0, inv_n));
        P = m2mul(P, from_f4(v1, inv_n));
    }
    if (i < end) {
        float4 v0 = A[i];
        P = m2mul(P, from_f4(v0, inv_n));
    }

    P = wave_combine(P);

    if ((threadIdx.x & 63) == 0) {
        int w = t >> 6;
        part[4 * w + 0] = P.a;
        part[4 * w + 1] = P.b;
        part[4 * w + 2] = P.c;
        part[4 * w + 3] = P.d;
    }
}

// 256 threads, 1 block. nw partials (nw % 256 == 0). Each thread serially
// combines nw/256 consecutive partials, wave tree -> 4 wave partials -> LDS
// -> thread 0 combines in wave order.
__global__ void __launch_bounds__(256) prodchain_phase2(
    const double* __restrict__ part, int nw, float* __restrict__ out)
{
    __shared__ double lds[4 * 4];
    const int t = threadIdx.x;
    const int per = nw >> 8;           // partials per thread
    M2 P = {1.0, 0.0, 0.0, 1.0};
    const int base = t * per;
    for (int i = base; i < base + per; ++i) {
        M2 Q = { part[4 * i + 0], part[4 * i + 1],
                 part[4 * i + 2], part[4 * i + 3] };
        P = m2mul(P, Q);
    }

    P = wave_combine(P);

    const int w = t >> 6;
    if ((t & 63) == 0) {
        lds[4 * w + 0] = P.a;
        lds[4 * w + 1] = P.b;
        lds[4 * w + 2] = P.c;
        lds[4 * w + 3] = P.d;
    }
    __syncthreads();

    if (t == 0) {
        M2 R = { lds[0], lds[1], lds[2], lds[3] };
        #pragma unroll
        for (int w2 = 1; w2 < 4; ++w2) {
            M2 Q = { lds[4 * w2 + 0], lds[4 * w2 + 1],
                     lds[4 * w2 + 2], lds[4 * w2 + 3] };
            R = m2mul(R, Q);
        }
        out[0] = (float)R.a;
        out[1] = (float)R.b;
        out[2] = (float)R.c;
        out[3] = (float)R.d;
    }
}

extern "C" void kernel_launch(void* const* d_in, const int* in_sizes, int n_in,
                              void* d_out, int out_size, void* d_ws, size_t ws_size,
                              hipStream_t stream) {
    const float4* A = (const float4*)d_in[0];
    const int n = in_sizes[0] / 4;          // number of 2x2 matrices
    double* part = (double*)d_ws;           // N_WAVES * 4 doubles = 256 KB
    const int chunk = (n + T_TOTAL - 1) / T_TOTAL;

    prodchain_phase1<<<P1_BLOCKS, P1_TPB, 0, stream>>>(A, n, chunk, part);
    prodchain_phase2<<<1, 256, 0, stream>>>(part, N_WAVES, (float*)d_out);
}

// Round 3
// 37.845 us; speedup vs baseline: 1.0624x; 1.0624x over previous
//
#include <hip/hip_runtime.h>

// X = prod_{i=0}^{n-1} (I + A_i/n), left-to-right, A: [N,2,2] f32 row-major.
// R2 post-mortem: occupancy 4x changed nothing -> phase1 is L1-transaction
// bound (64 distinct lines per wave-load with 160B/lane chunks). R3: stage
// each block's region in LDS with coalesced loads (16 lines/instr), consume
// contiguous per-thread chunks from LDS. chunk=5 (odd) -> bank-balanced.

struct M2 { double a, b, c, d; };  // [[a,b],[c,d]]

__device__ __forceinline__ M2 m2mul(const M2& X, const M2& Y) {
    M2 r;
    r.a = fma(X.a, Y.a, X.b * Y.c);
    r.b = fma(X.a, Y.b, X.b * Y.d);
    r.c = fma(X.c, Y.a, X.d * Y.c);
    r.d = fma(X.c, Y.b, X.d * Y.d);
    return r;
}

__device__ __forceinline__ M2 from_f4(float4 v, double inv_n) {
    M2 M;
    M.a = fma((double)v.x, inv_n, 1.0);
    M.b = (double)v.y * inv_n;
    M.c = (double)v.z * inv_n;
    M.d = fma((double)v.w, inv_n, 1.0);
    return M;
}

// Ordered wave tree combine: lower lane = earlier chunk = left operand.
__device__ __forceinline__ M2 wave_combine(M2 P) {
    #pragma unroll
    for (int off = 1; off < 64; off <<= 1) {
        M2 Q;
        Q.a = __shfl_down(P.a, off);
        Q.b = __shfl_down(P.b, off);
        Q.c = __shfl_down(P.c, off);
        Q.d = __shfl_down(P.d, off);
        P = m2mul(P, Q);
    }
    return P;
}

#define CHUNK 5
#define P1_TPB 256
#define TILE (P1_TPB * CHUNK)          // 1280 matrices per block, 20 KB LDS

__global__ void __launch_bounds__(P1_TPB) prodchain_phase1(
    const float4* __restrict__ A, int n, double* __restrict__ part)
{
    __shared__ float4 tile[TILE];
    const int tid = threadIdx.x;
    const int blockStart = blockIdx.x * TILE;
    const double inv_n = 1.0 / (double)n;

    // Coalesced stage: granule k*256+tid; consecutive lanes 16B apart.
    float4 r[CHUNK];
    #pragma unroll
    for (int k = 0; k < CHUNK; ++k) {
        int g = blockStart + k * P1_TPB + tid;
        r[k] = (g < n) ? A[g] : make_float4(0.f, 0.f, 0.f, 0.f);
    }
    #pragma unroll
    for (int k = 0; k < CHUNK; ++k)
        tile[k * P1_TPB + tid] = r[k];
    __syncthreads();

    // Consume contiguous per-thread chunk from LDS (bank-balanced: 5 odd).
    M2 P = {1.0, 0.0, 0.0, 1.0};
    const int base = tid * CHUNK;
    #pragma unroll
    for (int j = 0; j < CHUNK; ++j) {
        int gi = blockStart + base + j;
        if (gi < n) P = m2mul(P, from_f4(tile[base + j], inv_n));
    }

    P = wave_combine(P);

    if ((tid & 63) == 0) {
        int w = (blockIdx.x * P1_TPB + tid) >> 6;
        part[4 * w + 0] = P.a;
        part[4 * w + 1] = P.b;
        part[4 * w + 2] = P.c;
        part[4 * w + 3] = P.d;
    }
}

#define P2_TPB 1024

// One block, 1024 threads. nw wave-partials; per-thread 16 serial combines
// (identity for OOB), wave tree, LDS cross-wave combine in wave order.
__global__ void __launch_bounds__(P2_TPB) prodchain_phase2(
    const double* __restrict__ part, int nw, float* __restrict__ out)
{
    __shared__ double lds[4 * (P2_TPB / 64)];
    const int t = threadIdx.x;
    const int per = (nw + P2_TPB - 1) / P2_TPB;
    M2 P = {1.0, 0.0, 0.0, 1.0};
    const int base = t * per;
    for (int i = base; i < base + per; ++i) {
        if (i < nw) {
            M2 Q = { part[4 * i + 0], part[4 * i + 1],
                     part[4 * i + 2], part[4 * i + 3] };
            P = m2mul(P, Q);
        }
    }

    P = wave_combine(P);

    const int w = t >> 6;
    if ((t & 63) == 0) {
        lds[4 * w + 0] = P.a;
        lds[4 * w + 1] = P.b;
        lds[4 * w + 2] = P.c;
        lds[4 * w + 3] = P.d;
    }
    __syncthreads();

    if (t == 0) {
        M2 R = { lds[0], lds[1], lds[2], lds[3] };
        #pragma unroll
        for (int w2 = 1; w2 < P2_TPB / 64; ++w2) {
            M2 Q = { lds[4 * w2 + 0], lds[4 * w2 + 1],
                     lds[4 * w2 + 2], lds[4 * w2 + 3] };
            R = m2mul(R, Q);
        }
        out[0] = (float)R.a;
        out[1] = (float)R.b;
        out[2] = (float)R.c;
        out[3] = (float)R.d;
    }
}

extern "C" void kernel_launch(void* const* d_in, const int* in_sizes, int n_in,
                              void* d_out, int out_size, void* d_ws, size_t ws_size,
                              hipStream_t stream) {
    const float4* A = (const float4*)d_in[0];
    const int n = in_sizes[0] / 4;                    // 5,000,000 matrices
    double* part = (double*)d_ws;
    const int blocks = (n + TILE - 1) / TILE;         // 3907
    const int nw = (blocks * P1_TPB) >> 6;            // wave partials

    prodchain_phase1<<<blocks, P1_TPB, 0, stream>>>(A, n, part);
    prodchain_phase2<<<1, P2_TPB, 0, stream>>>(part, nw, (float*)d_out);
}

// Round 4
// 23.603 us; speedup vs baseline: 1.7034x; 1.6034x over previous
//
#include <hip/hip_runtime.h>

// X = prod_{i=0}^{n-1} (I + A_i/n), left-to-right, A: [N,2,2] f32 row-major.
// R3 post-mortem: phase1 rebuild moved total only 2.4us -> suspect phase2
// single-block strided tail (~20us, 64 lines/wave-load on one CU).
// R4: phase1 emits ONE partial per block (in-block cross-wave combine);
// phase2 becomes a 2-level lane-per-partial tree with coalesced loads.

struct M2 { double a, b, c, d; };  // [[a,b],[c,d]]

__device__ __forceinline__ M2 m2mul(const M2& X, const M2& Y) {
    M2 r;
    r.a = fma(X.a, Y.a, X.b * Y.c);
    r.b = fma(X.a, Y.b, X.b * Y.d);
    r.c = fma(X.c, Y.a, X.d * Y.c);
    r.d = fma(X.c, Y.b, X.d * Y.d);
    return r;
}

__device__ __forceinline__ M2 from_f4(float4 v, double inv_n) {
    M2 M;
    M.a = fma((double)v.x, inv_n, 1.0);
    M.b = (double)v.y * inv_n;
    M.c = (double)v.z * inv_n;
    M.d = fma((double)v.w, inv_n, 1.0);
    return M;
}

// Ordered wave tree combine: lower lane = earlier chunk = left operand.
__device__ __forceinline__ M2 wave_combine(M2 P) {
    #pragma unroll
    for (int off = 1; off < 64; off <<= 1) {
        M2 Q;
        Q.a = __shfl_down(P.a, off);
        Q.b = __shfl_down(P.b, off);
        Q.c = __shfl_down(P.c, off);
        Q.d = __shfl_down(P.d, off);
        P = m2mul(P, Q);
    }
    return P;
}

__device__ __forceinline__ M2 load_m2(const double* p) {
    double2 lo = *reinterpret_cast<const double2*>(p);
    double2 hi = *reinterpret_cast<const double2*>(p + 2);
    M2 Q = { lo.x, lo.y, hi.x, hi.y };
    return Q;
}

__device__ __forceinline__ void store_m2(double* p, const M2& P) {
    *reinterpret_cast<double2*>(p)     = double2{ P.a, P.b };
    *reinterpret_cast<double2*>(p + 2) = double2{ P.c, P.d };
}

#define CHUNK 5
#define P1_TPB 256
#define TILE (P1_TPB * CHUNK)          // 1280 matrices per block, 20 KB LDS

__global__ void __launch_bounds__(P1_TPB) prodchain_phase1(
    const float4* __restrict__ A, int n, double* __restrict__ part)
{
    __shared__ float4 tile[TILE];
    __shared__ double bl[4 * 4];       // 4 wave partials
    const int tid = threadIdx.x;
    const int blockStart = blockIdx.x * TILE;
    const double inv_n = 1.0 / (double)n;

    // Coalesced stage: granule k*256+tid; consecutive lanes 16B apart.
    float4 r[CHUNK];
    #pragma unroll
    for (int k = 0; k < CHUNK; ++k) {
        int g = blockStart + k * P1_TPB + tid;
        r[k] = (g < n) ? A[g] : make_float4(0.f, 0.f, 0.f, 0.f);
    }
    #pragma unroll
    for (int k = 0; k < CHUNK; ++k)
        tile[k * P1_TPB + tid] = r[k];
    __syncthreads();

    // Consume contiguous per-thread chunk from LDS. Lane stride 80B ->
    // 16B-group pattern (5l)%8 is a permutation: conflict-free b128 reads.
    M2 P = {1.0, 0.0, 0.0, 1.0};
    const int base = tid * CHUNK;
    #pragma unroll
    for (int j = 0; j < CHUNK; ++j) {
        int gi = blockStart + base + j;
        if (gi < n) P = m2mul(P, from_f4(tile[base + j], inv_n));
    }

    P = wave_combine(P);

    const int w = tid >> 6;
    if ((tid & 63) == 0) {
        bl[4 * w + 0] = P.a;
        bl[4 * w + 1] = P.b;
        bl[4 * w + 2] = P.c;
        bl[4 * w + 3] = P.d;
    }
    __syncthreads();

    if (tid == 0) {
        M2 R = { bl[0], bl[1], bl[2], bl[3] };
        #pragma unroll
        for (int w2 = 1; w2 < 4; ++w2) {
            M2 Q = { bl[4 * w2 + 0], bl[4 * w2 + 1],
                     bl[4 * w2 + 2], bl[4 * w2 + 3] };
            R = m2mul(R, Q);
        }
        store_m2(&part[4 * blockIdx.x], R);
    }
}

// Lane-per-partial ordered reduce: block b combines partials
// [b*64, b*64+64) (identity for OOB) into out_part[b]. Coalesced:
// consecutive lanes read consecutive 32B records.
__global__ void __launch_bounds__(64) prodchain_reduce(
    const double* __restrict__ in_part, int np, double* __restrict__ out_part)
{
    const int l = threadIdx.x;
    const int idx = blockIdx.x * 64 + l;
    M2 P = {1.0, 0.0, 0.0, 1.0};
    if (idx < np) P = load_m2(&in_part[4 * idx]);

    P = wave_combine(P);

    if (l == 0) store_m2(&out_part[4 * blockIdx.x], P);
}

__global__ void __launch_bounds__(64) prodchain_final(
    const double* __restrict__ in_part, int np, float* __restrict__ out)
{
    const int l = threadIdx.x;
    M2 P = {1.0, 0.0, 0.0, 1.0};
    if (l < np) P = load_m2(&in_part[4 * l]);

    P = wave_combine(P);

    if (l == 0) {
        out[0] = (float)P.a;
        out[1] = (float)P.b;
        out[2] = (float)P.c;
        out[3] = (float)P.d;
    }
}

extern "C" void kernel_launch(void* const* d_in, const int* in_sizes, int n_in,
                              void* d_out, int out_size, void* d_ws, size_t ws_size,
                              hipStream_t stream) {
    const float4* A = (const float4*)d_in[0];
    const int n = in_sizes[0] / 4;                    // 5,000,000 matrices
    const int nb1 = (n + TILE - 1) / TILE;            // 3907 block partials
    const int nb2 = (nb1 + 63) / 64;                  // 62 level-2 partials

    double* part1 = (double*)d_ws;                    // 3907 * 32 B = 125 KB
    double* part2 = part1 + 4 * 4096;                 // offset 128 KB

    prodchain_phase1<<<nb1, P1_TPB, 0, stream>>>(A, n, part1);
    prodchain_reduce<<<nb2, 64, 0, stream>>>(part1, nb1, part2);
    prodchain_final<<<1, 64, 0, stream>>>(part2, nb2, (float*)d_out);
}